// Round 1
// 726.778 us; speedup vs baseline: 1.1550x; 1.1550x over previous
//
#include <hip/hip_runtime.h>
#include <math.h>

typedef unsigned short ushort_t;
typedef __attribute__((ext_vector_type(8))) short bf16x8;
typedef __attribute__((ext_vector_type(4))) float f32x4;

#define DIM    1536
#define NH     12
#define HD     128
#define SEQ    1560
#define CURS   4680
#define NKEY   6240
#define GW     52
#define SFRAME 3
#define EPSV   1e-6f
#define QSCALE 0.08838834764831845f
#define KSPLIT 2
#define NCHUNK 98
#define CPS    49      // chunks per split
#define QPAD   1600    // 25 tiles * 64
#define MPAD   1664    // 13 tiles * 128 (gemm row padding)

__device__ __forceinline__ ushort_t f2bf(float f) {
    union { float f; unsigned int u; } x; x.f = f;
    unsigned int r = x.u + 0x7fffu + ((x.u >> 16) & 1u);
    return (ushort_t)(r >> 16);
}

__device__ __forceinline__ void gld_lds16(const ushort_t* gsrc, ushort_t* ldst) {
    __builtin_amdgcn_global_load_lds(
        (const __attribute__((address_space(1))) unsigned int*)gsrc,
        (__attribute__((address_space(3))) unsigned int*)ldst,
        16, 0, 0);
}

// ============ fp32 -> bf16 bulk convert (vectorized, 8 elems/thread) ============
__global__ __launch_bounds__(256)
void f32_to_bf16_k(const float* __restrict__ in, ushort_t* __restrict__ out, int n8)
{
    const int i = blockIdx.x * 256 + threadIdx.x;
    if (i >= n8) return;
    float4 a = ((const float4*)in)[2*i];
    float4 b = ((const float4*)in)[2*i + 1];
    union { ushort_t u[8]; bf16x8 v; } uu;
    uu.u[0]=f2bf(a.x); uu.u[1]=f2bf(a.y); uu.u[2]=f2bf(a.z); uu.u[3]=f2bf(a.w);
    uu.u[4]=f2bf(b.x); uu.u[5]=f2bf(b.y); uu.u[6]=f2bf(b.z); uu.u[7]=f2bf(b.w);
    ((bf16x8*)out)[i] = uu.v;
}

// ============ m97-structure bf16 GEMM: C[M,N] = A[M,K] @ B[N,K]^T + bias ============
// 128x128 tile, BK=32, 4 waves (each 64x64 = 4x4 frags), global_load_lds staging.
// QKV=1: N=4608 fused; tiles 0-11 -> Q (fp32), 12-23 -> K (fp32), 24-35 -> V (bf16).
// QKV=0: single fp32 output (out-projection), grid.x = 12.
template<int QKV>
__global__ __launch_bounds__(256) void gemm128(
    const ushort_t* __restrict__ A, const ushort_t* __restrict__ B,
    const float* __restrict__ b0, const float* __restrict__ b1, const float* __restrict__ b2,
    float* __restrict__ outQ, float* __restrict__ outK, ushort_t* __restrict__ outV,
    int M, int K)
{
    __shared__ ushort_t As[128*32];   // 8KB, linear (global_load_lds needs contiguous)
    __shared__ ushort_t Bs[128*32];

    const int t = threadIdx.x;
    const int w = t >> 6, l = t & 63, quad = l >> 4, l15 = l & 15;
    const int bm = blockIdx.y * 128;
    const int bn = blockIdx.x * 128;
    const int wm = (w & 1) << 6, wn = (w >> 1) << 6;

    // staging role: wave w covers LDS bytes [w*2048, +2048) = tile rows [w*32, +32)
    const int srow = (w << 5) + (l >> 2);     // call-0 row
    const int scol = (l & 3) << 3;
    const ushort_t* Ag = A + (size_t)(bm + srow) * K + scol;
    const ushort_t* Bg = B + (size_t)(bn + srow) * K + scol;
    ushort_t* AsB = &As[w << 10];             // wave-uniform LDS base (elements)
    ushort_t* BsB = &Bs[w << 10];

    f32x4 acc[4][4] = {};

    for (int k0 = 0; k0 < K; k0 += 32) {
        __syncthreads();                      // prior frag reads done before overwrite
        gld_lds16(Ag + k0,          AsB);
        gld_lds16(Ag + k0 + 16*K,   AsB + 512);
        gld_lds16(Bg + k0,          BsB);
        gld_lds16(Bg + k0 + 16*K,   BsB + 512);
        __syncthreads();                      // compiler drains vmcnt before barrier

        bf16x8 af[4], bfv[4];
        #pragma unroll
        for (int i = 0; i < 4; ++i) {
            af[i]  = *(const bf16x8*)&As[(wm + i*16 + l15) * 32 + quad*8];
            bfv[i] = *(const bf16x8*)&Bs[(wn + i*16 + l15) * 32 + quad*8];
        }
        #pragma unroll
        for (int mi = 0; mi < 4; ++mi)
            #pragma unroll
            for (int ni = 0; ni < 4; ++ni)
                acc[mi][ni] = __builtin_amdgcn_mfma_f32_16x16x32_bf16(af[mi], bfv[ni], acc[mi][ni], 0,0,0);
    }

    // epilogue: C/D layout col=lane&15, row=quad*4+reg (m89)
    int mat, c0;
    if (QKV) { mat = blockIdx.x / 12; c0 = (blockIdx.x % 12) * 128; }
    else     { mat = 0;               c0 = blockIdx.x * 128; }
    const float* bias = QKV ? (mat == 0 ? b0 : (mat == 1 ? b1 : b2)) : b0;
    float* outF = (QKV && mat == 1) ? outK : outQ;

    #pragma unroll
    for (int ni = 0; ni < 4; ++ni) {
        const int col = c0 + wn + ni*16 + l15;
        const float bc = bias[col];
        #pragma unroll
        for (int mi = 0; mi < 4; ++mi) {
            #pragma unroll
            for (int r = 0; r < 4; ++r) {
                const int row = bm + wm + mi*16 + quad*4 + r;
                if (row < M) {
                    const float v = acc[mi][ni][r] + bc;
                    if (QKV && mat == 2) outV[(size_t)row * DIM + col] = f2bf(v);
                    else                 outF[(size_t)row * DIM + col] = v;
                }
            }
        }
    }
}

// ============ RMSNorm + RoPE, fp32 in -> bf16 out (scale folded in) ============
__global__ __launch_bounds__(256)
void rmsnorm_rope(const float* __restrict__ buf, const float* __restrict__ g,
                  const float* __restrict__ freqs, ushort_t* __restrict__ out,
                  float scale)
{
    const int tok = blockIdx.x;
    const int t = threadIdx.x;
    const float* row = buf + (size_t)tok * DIM;

    float2 xv[3];
    float ss = 0.f;
    #pragma unroll
    for (int i = 0; i < 3; ++i) {
        xv[i] = ((const float2*)row)[t + 256*i];
        ss += xv[i].x*xv[i].x + xv[i].y*xv[i].y;
    }
    #pragma unroll
    for (int off = 32; off > 0; off >>= 1) ss += __shfl_xor(ss, off);
    __shared__ float part[4];
    __shared__ float invs;
    if ((t & 63) == 0) part[t >> 6] = ss;
    __syncthreads();
    if (t == 0) invs = rsqrtf((part[0]+part[1]+part[2]+part[3]) * (1.0f/DIM) + EPSV);
    __syncthreads();
    const float inv = invs * scale;   // scale commutes through rotation
    const int hh = tok / GW;
    const int ww = tok % GW;
    #pragma unroll
    for (int i = 0; i < 3; ++i) {
        const int p = t + 256*i;      // pair index; j = p%64
        const int j = p & 63;
        const int rsel = (j < 22) ? SFRAME : ((j < 43) ? hh : ww);
        const float ang = freqs[rsel*64 + j];
        float sn, cs;
        sincosf(ang, &sn, &cs);
        const float a = xv[i].x * inv * g[2*p];
        const float b = xv[i].y * inv * g[2*p+1];
        const unsigned int lo = f2bf(a*cs - b*sn);
        const unsigned int hi = f2bf(a*sn + b*cs);
        ((unsigned int*)out)[(size_t)tok*768 + p] = (hi << 16) | lo;
    }
}

// ============ Build bf16 key window Kw[h][p][d] ============
__global__ __launch_bounds__(256)
void kwin_k(const float* __restrict__ kc, const ushort_t* __restrict__ kb,
            ushort_t* __restrict__ Kw)
{
    const int tid = blockIdx.x * 256 + threadIdx.x;   // 12*6240*16
    const int dc = tid & 15;
    const int hp = tid >> 4;
    const int p = hp % NKEY;
    const int h = hp / NKEY;
    ushort_t* outp = Kw + (size_t)tid * 8;
    if (p >= CURS) {
        *(bf16x8*)outp = *(const bf16x8*)(kb + (size_t)(p - CURS)*DIM + h*HD + dc*8);
    } else {
        const float* src = kc + ((size_t)p * NH + h) * HD + dc*8;
        float4 f0 = *(const float4*)src, f1 = *(const float4*)(src + 4);
        union { ushort_t u[8]; bf16x8 v; } uu;
        uu.u[0]=f2bf(f0.x); uu.u[1]=f2bf(f0.y); uu.u[2]=f2bf(f0.z); uu.u[3]=f2bf(f0.w);
        uu.u[4]=f2bf(f1.x); uu.u[5]=f2bf(f1.y); uu.u[6]=f2bf(f1.z); uu.u[7]=f2bf(f1.w);
        *(bf16x8*)outp = uu.v;
    }
}

// ============ Build transposed bf16 value window Vwt[h][d][p] ============
__global__ __launch_bounds__(256)
void kwin_v(const float* __restrict__ vc, const ushort_t* __restrict__ vb,
            ushort_t* __restrict__ Vwt)
{
    __shared__ ushort_t tile[64][40];
    const int t = threadIdx.x;
    const int bp = blockIdx.x, bd = blockIdx.y, h = blockIdx.z;
    const int p_loc = t >> 2, ds0 = (t & 3) * 8;
    const int pr = min(bp*64 + p_loc, NKEY-1);
    const int d = bd*32 + ds0;
    union { ushort_t u[8]; bf16x8 v; } uu;
    if (pr >= CURS) {
        uu.v = *(const bf16x8*)(vb + (size_t)(pr - CURS)*DIM + h*HD + d);
    } else {
        const float* src = vc + ((size_t)pr*NH + h)*HD + d;
        float4 f0 = *(const float4*)src, f1 = *(const float4*)(src+4);
        uu.u[0]=f2bf(f0.x); uu.u[1]=f2bf(f0.y); uu.u[2]=f2bf(f0.z); uu.u[3]=f2bf(f0.w);
        uu.u[4]=f2bf(f1.x); uu.u[5]=f2bf(f1.y); uu.u[6]=f2bf(f1.z); uu.u[7]=f2bf(f1.w);
    }
    *(bf16x8*)&tile[p_loc][ds0] = uu.v;
    __syncthreads();
    const int d_loc = t >> 3, ps = (t & 7) * 8;
    if (bp*64 + ps < NKEY) {
        union { ushort_t u[8]; bf16x8 v; } oo;
        #pragma unroll
        for (int i = 0; i < 8; ++i) oo.u[i] = tile[ps + i][d_loc];
        *(bf16x8*)(Vwt + ((size_t)h*HD + bd*32 + d_loc) * NKEY + bp*64 + ps) = oo.v;
    }
}

// ============ MFMA flash attention, split-K over key chunks ============
__global__ __launch_bounds__(256)
void attn_kernel(const ushort_t* __restrict__ qb, const ushort_t* __restrict__ Kw,
                 const ushort_t* __restrict__ Vwt, float* __restrict__ Op,
                 float* __restrict__ Ms, float* __restrict__ Ls)
{
    __shared__ ushort_t Ks[64][136];   // [key][d] pad 128->136
    __shared__ ushort_t Vs[128][72];   // [d][key] pad 64->72
    __shared__ float    Sc[64][68];    // scores fp32, pad 64->68
    __shared__ ushort_t Pb[64][72];    // P bf16, A-layout source
    __shared__ float mst[64], lst[64], alf[64];

    const int t = threadIdx.x;
    const int w = t >> 6, l = t & 63, quad = l >> 4, l15 = l & 15;
    const int h = blockIdx.y;
    const int q0 = blockIdx.x * 64;
    const int z = blockIdx.z;

    bf16x8 qf[4];   // A-frags: Q[m=lane&15][k=quad*8+j], 4 d-steps of 32
    {
        const int qrow = min(q0 + w*16 + l15, SEQ-1);
        const ushort_t* qp = qb + ((size_t)qrow*NH + h)*HD;
        #pragma unroll
        for (int s = 0; s < 4; ++s) qf[s] = *(const bf16x8*)(qp + s*32 + quad*8);
    }
    f32x4 o[8] = {};
    if (t < 64) { mst[t] = -1e30f; lst[t] = 0.f; }

    const ushort_t* Kwh = Kw  + (size_t)h * NKEY * HD;
    const ushort_t* Vwh = Vwt + (size_t)h * HD * NKEY;
    const int key_st = t >> 2, kd0 = (t & 3) * 32;   // K staging role
    const int vd = t >> 1,     vk0 = (t & 1) * 32;   // V staging role

    for (int c = z*CPS; c < (z+1)*CPS; ++c) {
        const int p0 = c * 64;
        bf16x8 kr[4], vr[4];
        {
            const ushort_t* kp = Kwh + (size_t)min(p0 + key_st, NKEY-1) * HD + kd0;
            #pragma unroll
            for (int i = 0; i < 4; ++i) kr[i] = *(const bf16x8*)(kp + i*8);
            const ushort_t* vp = Vwh + (size_t)vd * NKEY;
            #pragma unroll
            for (int i = 0; i < 4; ++i) {
                const int pk = min(p0 + vk0 + i*8, NKEY-8);
                vr[i] = *(const bf16x8*)(vp + pk);
            }
        }
        __syncthreads();   // (A) prior PV reads of Vs / softmax use of Pb done
        #pragma unroll
        for (int i = 0; i < 4; ++i) *(bf16x8*)&Ks[key_st][kd0 + i*8] = kr[i];
        #pragma unroll
        for (int i = 0; i < 4; ++i) *(bf16x8*)&Vs[vd][vk0 + i*8] = vr[i];
        __syncthreads();   // (B)

        // QK^T
        f32x4 sf[4];
        #pragma unroll
        for (int kb = 0; kb < 4; ++kb) { f32x4 zz = {0.f,0.f,0.f,0.f}; sf[kb] = zz; }
        #pragma unroll
        for (int s = 0; s < 4; ++s) {
            #pragma unroll
            for (int kb = 0; kb < 4; ++kb) {
                bf16x8 kf = *(const bf16x8*)&Ks[kb*16 + l15][s*32 + quad*8];
                sf[kb] = __builtin_amdgcn_mfma_f32_16x16x32_bf16(qf[s], kf, sf[kb], 0,0,0);
            }
        }
        #pragma unroll
        for (int kb = 0; kb < 4; ++kb) {
            const int pkey = p0 + kb*16 + l15;
            const bool valid = pkey < NKEY;
            #pragma unroll
            for (int r = 0; r < 4; ++r)
                Sc[w*16 + quad*4 + r][kb*16 + l15] = valid ? sf[kb][r] : -1e30f;
        }
        __syncthreads();   // (C)

        // distributed online softmax: 4 threads per q row
        {
            const int row = t >> 2, seg = t & 3;
            float sv[16];
            #pragma unroll
            for (int i = 0; i < 4; ++i) {
                float4 s4 = *(const float4*)&Sc[row][seg*16 + i*4];
                sv[i*4+0]=s4.x; sv[i*4+1]=s4.y; sv[i*4+2]=s4.z; sv[i*4+3]=s4.w;
            }
            float mx = sv[0];
            #pragma unroll
            for (int i = 1; i < 16; ++i) mx = fmaxf(mx, sv[i]);
            mx = fmaxf(mx, __shfl_xor(mx, 1));
            mx = fmaxf(mx, __shfl_xor(mx, 2));
            const float mo = mst[row];
            const float mn = fmaxf(mo, mx);
            float sum = 0.f;
            union { ushort_t u[8]; bf16x8 v; } pa, pc;
            #pragma unroll
            for (int i = 0; i < 8; ++i) { float e = __expf(sv[i]   - mn); sum += e; pa.u[i] = f2bf(e); }
            #pragma unroll
            for (int i = 0; i < 8; ++i) { float e = __expf(sv[8+i] - mn); sum += e; pc.u[i] = f2bf(e); }
            sum += __shfl_xor(sum, 1);
            sum += __shfl_xor(sum, 2);
            *(bf16x8*)&Pb[row][seg*16]     = pa.v;
            *(bf16x8*)&Pb[row][seg*16 + 8] = pc.v;
            if (seg == 0) {
                const float al = __expf(mo - mn);
                lst[row] = lst[row]*al + sum;
                mst[row] = mn;
                alf[row] = al;
            }
        }
        __syncthreads();   // (D)

        // PV
        {
            float ar[4];
            #pragma unroll
            for (int r = 0; r < 4; ++r) ar[r] = alf[w*16 + quad*4 + r];
            #pragma unroll
            for (int nb = 0; nb < 8; ++nb)
                #pragma unroll
                for (int r = 0; r < 4; ++r) o[nb][r] *= ar[r];
            #pragma unroll
            for (int ks = 0; ks < 2; ++ks) {
                bf16x8 pf = *(const bf16x8*)&Pb[w*16 + l15][ks*32 + quad*8];
                #pragma unroll
                for (int nb = 0; nb < 8; ++nb) {
                    bf16x8 vf = *(const bf16x8*)&Vs[nb*16 + l15][ks*32 + quad*8];
                    o[nb] = __builtin_amdgcn_mfma_f32_16x16x32_bf16(pf, vf, o[nb], 0,0,0);
                }
            }
        }
    }
    __syncthreads();
    {
        float* Opz = Op + (size_t)z * QPAD * NH * HD;
        #pragma unroll
        for (int nb = 0; nb < 8; ++nb) {
            const int col = nb*16 + l15;
            #pragma unroll
            for (int r = 0; r < 4; ++r) {
                const int row = q0 + w*16 + quad*4 + r;   // < 1600, padded
                Opz[((size_t)row*NH + h)*HD + col] = o[nb][r];
            }
        }
        if (t < 64) {
            const int row = q0 + t;
            Ms[(size_t)z*QPAD*NH + row*NH + h] = mst[t];
            Ls[(size_t)z*QPAD*NH + row*NH + h] = lst[t];
        }
    }
}

// ============ merge KSPLIT partials (log-sum-exp), bf16 out for out-proj GEMM ============
__global__ __launch_bounds__(256)
void merge_kernel(const float* __restrict__ Op, const float* __restrict__ Ms,
                  const float* __restrict__ Ls, ushort_t* __restrict__ abufb)
{
    const int tid = blockIdx.x*256 + threadIdx.x;   // 1560*12*32
    const int dq = tid & 31;
    const int h = (tid >> 5) % NH;
    const int q = tid / (NH*32);
    const size_t sidx = (size_t)q*NH + h;
    const float m0 = Ms[sidx], m1 = Ms[(size_t)QPAD*NH + sidx];
    const float l0 = Ls[sidx], l1 = Ls[(size_t)QPAD*NH + sidx];
    const float mm = fmaxf(m0, m1);
    const float w0 = __expf(m0 - mm), w1 = __expf(m1 - mm);
    const float inv = 1.0f / (l0*w0 + l1*w1);
    const size_t oidx = sidx*HD + dq*4;
    float4 a = *(const float4*)(Op + oidx);
    float4 b = *(const float4*)(Op + (size_t)QPAD*NH*HD + oidx);
    ushort4 r;
    r.x = f2bf((a.x*w0 + b.x*w1)*inv);
    r.y = f2bf((a.y*w0 + b.y*w1)*inv);
    r.z = f2bf((a.z*w0 + b.z*w1)*inv);
    r.w = f2bf((a.w*w0 + b.w*w1)*inv);
    *(ushort4*)(abufb + (size_t)q*DIM + h*HD + dq*4) = r;
}

extern "C" void kernel_launch(void* const* d_in, const int* in_sizes, int n_in,
                              void* d_out, int out_size, void* d_ws, size_t ws_size,
                              hipStream_t stream)
{
    const float* x     = (const float*)d_in[0];
    const float* freqs = (const float*)d_in[1];
    const float* wq    = (const float*)d_in[2];
    const float* bq    = (const float*)d_in[3];
    const float* wk    = (const float*)d_in[4];
    const float* bk    = (const float*)d_in[5];
    const float* wv    = (const float*)d_in[6];
    const float* bv    = (const float*)d_in[7];
    const float* wo    = (const float*)d_in[8];
    const float* bo    = (const float*)d_in[9];
    const float* gq    = (const float*)d_in[10];
    const float* gk    = (const float*)d_in[11];
    const float* kck   = (const float*)d_in[12];
    const float* kcv   = (const float*)d_in[13];

    char* ws = (char*)d_ws;
    const size_t SZ_B16 = (size_t)SEQ*DIM*2;          // 4,792,320
    const size_t SZ_KW  = (size_t)NH*NKEY*HD*2;       // 19,169,280
    const size_t SZ_OP  = (size_t)KSPLIT*QPAD*NH*HD*4;// 19,660,800
    const size_t SZ_ST  = (size_t)KSPLIT*QPAD*NH*4;   // 153,600
    const size_t SZ_AB  = (size_t)MPAD*DIM*2;         // 5,111,808 (xb & abufb alias)

    ushort_t* qb  = (ushort_t*)(ws);
    ushort_t* kb  = (ushort_t*)(ws + SZ_B16);
    ushort_t* vb  = (ushort_t*)(ws + 2*SZ_B16);
    ushort_t* Kw  = (ushort_t*)(ws + 3*SZ_B16);
    ushort_t* Vwt = (ushort_t*)(ws + 3*SZ_B16 + SZ_KW);
    float*    Opb = (float*)   (ws + 3*SZ_B16 + 2*SZ_KW);
    float*    Msp = (float*)   (ws + 3*SZ_B16 + 2*SZ_KW + SZ_OP);
    float*    Lsp = (float*)   (ws + 3*SZ_B16 + 2*SZ_KW + SZ_OP + SZ_ST);
    ushort_t* abufb=(ushort_t*)(ws + 3*SZ_B16 + 2*SZ_KW + SZ_OP + 2*SZ_ST);
    ushort_t* wob = (ushort_t*)(ws + 3*SZ_B16 + 2*SZ_KW + SZ_OP + 2*SZ_ST + SZ_AB);
    // aliases (stream-ordered safe):
    ushort_t* xb   = abufb;   // xb dead before merge writes abufb
    ushort_t* Wqkv = Kw;      // Wqkv dead before kwin_k writes Kw
    float*    qf   = Opb;     // qf/kf dead before attn writes Opb
    float*    kf   = Opb + (size_t)SEQ*DIM;

    dim3 blk(256);
    const int XN8 = SEQ*DIM/8;      // 299,520
    const int WN8 = DIM*DIM/8;      // 294,912
    const size_t WE = (size_t)DIM*DIM;

    // --- bf16 pre-conversion (once) ---
    hipLaunchKernelGGL(f32_to_bf16_k, dim3((XN8+255)/256), blk, 0, stream, x,  xb,           XN8);
    hipLaunchKernelGGL(f32_to_bf16_k, dim3((WN8+255)/256), blk, 0, stream, wq, Wqkv,         WN8);
    hipLaunchKernelGGL(f32_to_bf16_k, dim3((WN8+255)/256), blk, 0, stream, wk, Wqkv + WE,    WN8);
    hipLaunchKernelGGL(f32_to_bf16_k, dim3((WN8+255)/256), blk, 0, stream, wv, Wqkv + 2*WE,  WN8);
    hipLaunchKernelGGL(f32_to_bf16_k, dim3((WN8+255)/256), blk, 0, stream, wo, wob,          WN8);

    // --- fused QKV projection: [1560,1536] @ [4608,1536]^T ---
    hipLaunchKernelGGL((gemm128<1>), dim3(36, 13), blk, 0, stream,
                       xb, Wqkv, bq, bk, bv, qf, kf, vb, SEQ, DIM);

    hipLaunchKernelGGL(rmsnorm_rope, dim3(SEQ), blk, 0, stream, qf, gq, freqs, qb, QSCALE);
    hipLaunchKernelGGL(rmsnorm_rope, dim3(SEQ), blk, 0, stream, kf, gk, freqs, kb, 1.0f);
    hipLaunchKernelGGL(kwin_k, dim3(NH*NKEY*16/256), blk, 0, stream, kck, kb, Kw);
    hipLaunchKernelGGL(kwin_v, dim3(98, 4, NH), blk, 0, stream, kcv, vb, Vwt);
    hipLaunchKernelGGL(attn_kernel, dim3((SEQ+63)/64, NH, KSPLIT), blk, 0, stream,
                       qb, Kw, Vwt, Opb, Msp, Lsp);
    hipLaunchKernelGGL(merge_kernel, dim3(SEQ*NH*32/256), blk, 0, stream, Opb, Msp, Lsp, abufb);

    // --- output projection ---
    hipLaunchKernelGGL((gemm128<0>), dim3(12, 13), blk, 0, stream,
                       abufb, wob, bo, bo, bo, (float*)d_out, (float*)d_out, (ushort_t*)nullptr, SEQ, DIM);
}

// Round 2
// 694.244 us; speedup vs baseline: 1.2091x; 1.0469x over previous
//
#include <hip/hip_runtime.h>
#include <math.h>

typedef unsigned short ushort_t;
typedef __attribute__((ext_vector_type(8))) short bf16x8;
typedef __attribute__((ext_vector_type(4))) float f32x4;

#define DIM    1536
#define NH     12
#define HD     128
#define SEQ    1560
#define CURS   4680
#define NKEY   6240
#define GW     52
#define SFRAME 3
#define EPSV   1e-6f
#define QSCALE 0.08838834764831845f
#define KSPLIT 2
#define NCHUNK 98
#define CPS    49      // chunks per split
#define QPAD   1600    // 25 tiles * 64
#define MPAD   1664    // 13 tiles * 128 (gemm row padding)

__device__ __forceinline__ ushort_t f2bf(float f) {
    union { float f; unsigned int u; } x; x.f = f;
    unsigned int r = x.u + 0x7fffu + ((x.u >> 16) & 1u);
    return (ushort_t)(r >> 16);
}

__device__ __forceinline__ unsigned int cvt_pk_bf16(float lo, float hi) {
    unsigned int r;
    asm("v_cvt_pk_bf16_f32 %0, %1, %2" : "=v"(r) : "v"(lo), "v"(hi));
    return r;
}

__device__ __forceinline__ void gld_lds16(const ushort_t* gsrc, ushort_t* ldst) {
    __builtin_amdgcn_global_load_lds(
        (const __attribute__((address_space(1))) unsigned int*)gsrc,
        (__attribute__((address_space(3))) unsigned int*)ldst,
        16, 0, 0);
}

// ============ fused fp32 -> bf16 bulk convert: x, wq, wk, wv, wo in one launch ============
#define XN8 (SEQ*DIM/8)      // 299,520 -> 1170 blocks
#define WN8 (DIM*DIM/8)      // 294,912 -> 1152 blocks
__global__ __launch_bounds__(256)
void conv5(const float* __restrict__ x,  const float* __restrict__ wq,
           const float* __restrict__ wk, const float* __restrict__ wv,
           const float* __restrict__ wo,
           ushort_t* __restrict__ xb, ushort_t* __restrict__ wqkv,
           ushort_t* __restrict__ wob)
{
    const int b = blockIdx.x;
    const float* src; ushort_t* dst; int idx;
    if (b < 1170) { src = x; dst = xb; idx = b*256 + threadIdx.x; if (idx >= XN8) return; }
    else {
        const int k = (b - 1170) / 1152, r = (b - 1170) % 1152;
        idx = r*256 + threadIdx.x;
        if      (k == 0) { src = wq; dst = wqkv; }
        else if (k == 1) { src = wk; dst = wqkv + (size_t)DIM*DIM; }
        else if (k == 2) { src = wv; dst = wqkv + 2*(size_t)DIM*DIM; }
        else             { src = wo; dst = wob; }
    }
    float4 a = ((const float4*)src)[2*(size_t)idx];
    float4 c = ((const float4*)src)[2*(size_t)idx + 1];
    union { ushort_t u[8]; bf16x8 v; } uu;
    uu.u[0]=f2bf(a.x); uu.u[1]=f2bf(a.y); uu.u[2]=f2bf(a.z); uu.u[3]=f2bf(a.w);
    uu.u[4]=f2bf(c.x); uu.u[5]=f2bf(c.y); uu.u[6]=f2bf(c.z); uu.u[7]=f2bf(c.w);
    ((bf16x8*)dst)[idx] = uu.v;
}

// ============ m97-structure bf16 GEMM: C[M,N] = A[M,K] @ B[N,K]^T + bias ============
template<int QKV>
__global__ __launch_bounds__(256) void gemm128(
    const ushort_t* __restrict__ A, const ushort_t* __restrict__ B,
    const float* __restrict__ b0, const float* __restrict__ b1, const float* __restrict__ b2,
    float* __restrict__ outQ, float* __restrict__ outK, ushort_t* __restrict__ outV,
    int M, int K)
{
    __shared__ ushort_t As[128*32];   // 8KB, linear (global_load_lds needs contiguous)
    __shared__ ushort_t Bs[128*32];

    const int t = threadIdx.x;
    const int w = t >> 6, l = t & 63, quad = l >> 4, l15 = l & 15;
    const int bm = blockIdx.y * 128;
    const int bn = blockIdx.x * 128;
    const int wm = (w & 1) << 6, wn = (w >> 1) << 6;

    const int srow = (w << 5) + (l >> 2);
    const int scol = (l & 3) << 3;
    const ushort_t* Ag = A + (size_t)(bm + srow) * K + scol;
    const ushort_t* Bg = B + (size_t)(bn + srow) * K + scol;
    ushort_t* AsB = &As[w << 10];
    ushort_t* BsB = &Bs[w << 10];

    f32x4 acc[4][4] = {};

    for (int k0 = 0; k0 < K; k0 += 32) {
        __syncthreads();
        gld_lds16(Ag + k0,          AsB);
        gld_lds16(Ag + k0 + 16*K,   AsB + 512);
        gld_lds16(Bg + k0,          BsB);
        gld_lds16(Bg + k0 + 16*K,   BsB + 512);
        __syncthreads();

        bf16x8 af[4], bfv[4];
        #pragma unroll
        for (int i = 0; i < 4; ++i) {
            af[i]  = *(const bf16x8*)&As[(wm + i*16 + l15) * 32 + quad*8];
            bfv[i] = *(const bf16x8*)&Bs[(wn + i*16 + l15) * 32 + quad*8];
        }
        #pragma unroll
        for (int mi = 0; mi < 4; ++mi)
            #pragma unroll
            for (int ni = 0; ni < 4; ++ni)
                acc[mi][ni] = __builtin_amdgcn_mfma_f32_16x16x32_bf16(af[mi], bfv[ni], acc[mi][ni], 0,0,0);
    }

    int mat, c0;
    if (QKV) { mat = blockIdx.x / 12; c0 = (blockIdx.x % 12) * 128; }
    else     { mat = 0;               c0 = blockIdx.x * 128; }
    const float* bias = QKV ? (mat == 0 ? b0 : (mat == 1 ? b1 : b2)) : b0;
    float* outF = (QKV && mat == 1) ? outK : outQ;

    #pragma unroll
    for (int ni = 0; ni < 4; ++ni) {
        const int col = c0 + wn + ni*16 + l15;
        const float bc = bias[col];
        #pragma unroll
        for (int mi = 0; mi < 4; ++mi) {
            #pragma unroll
            for (int r = 0; r < 4; ++r) {
                const int row = bm + wm + mi*16 + quad*4 + r;
                if (row < M) {
                    const float v = acc[mi][ni][r] + bc;
                    if (QKV && mat == 2) outV[(size_t)row * DIM + col] = f2bf(v);
                    else                 outF[(size_t)row * DIM + col] = v;
                }
            }
        }
    }
}

// ============ fused RMSNorm + RoPE for q and k (grid.y selects path) ============
// q path -> qb[tok][NH*HD] bf16 (QSCALE folded); k path -> directly into Kw tail rows.
__global__ __launch_bounds__(256)
void rms2(const float* __restrict__ qf, const float* __restrict__ kf,
          const float* __restrict__ gq, const float* __restrict__ gk,
          const float* __restrict__ freqs, ushort_t* __restrict__ qb,
          unsigned int* __restrict__ KwU)
{
    const int tok = blockIdx.x;
    const int path = blockIdx.y;            // 0 = q, 1 = k
    const int t = threadIdx.x;
    const float* row = (path ? kf : qf) + (size_t)tok * DIM;
    const float* g = path ? gk : gq;
    const float scale = path ? 1.0f : QSCALE;

    float2 xv[3];
    float ss = 0.f;
    #pragma unroll
    for (int i = 0; i < 3; ++i) {
        xv[i] = ((const float2*)row)[t + 256*i];
        ss += xv[i].x*xv[i].x + xv[i].y*xv[i].y;
    }
    #pragma unroll
    for (int off = 32; off > 0; off >>= 1) ss += __shfl_xor(ss, off);
    __shared__ float part[4];
    __shared__ float invs;
    if ((t & 63) == 0) part[t >> 6] = ss;
    __syncthreads();
    if (t == 0) invs = rsqrtf((part[0]+part[1]+part[2]+part[3]) * (1.0f/DIM) + EPSV);
    __syncthreads();
    const float inv = invs * scale;
    const int hh = tok / GW;
    const int ww = tok % GW;
    #pragma unroll
    for (int i = 0; i < 3; ++i) {
        const int p = t + 256*i;      // d-pair index 0..767
        const int j = p & 63;
        const int rsel = (j < 22) ? SFRAME : ((j < 43) ? hh : ww);
        const float ang = freqs[rsel*64 + j];
        float sn, cs;
        sincosf(ang, &sn, &cs);
        const float a = xv[i].x * inv * g[2*p];
        const float b = xv[i].y * inv * g[2*p+1];
        const unsigned int lo = f2bf(a*cs - b*sn);
        const unsigned int hi = f2bf(a*sn + b*cs);
        const unsigned int word = (hi << 16) | lo;
        if (!path) {
            ((unsigned int*)qb)[(size_t)tok*768 + p] = word;
        } else {
            const int head = p >> 6;      // 64 pairs per head
            const int dp = p & 63;
            KwU[((size_t)head*NKEY + CURS + tok)*64 + dp] = word;
        }
    }
}

// ============ Build bf16 key window Kw[h][p][d] — cache rows only (p < CURS) ============
__global__ __launch_bounds__(256)
void kwin_k(const float* __restrict__ kc, ushort_t* __restrict__ Kw)
{
    const int tid = blockIdx.x * 256 + threadIdx.x;   // 12*4680*16
    const int dc = tid & 15;
    const int hp = tid >> 4;
    const int p = hp % CURS;
    const int h = hp / CURS;
    const float* src = kc + ((size_t)p * NH + h) * HD + dc*8;
    float4 f0 = *(const float4*)src, f1 = *(const float4*)(src + 4);
    union { ushort_t u[8]; bf16x8 v; } uu;
    uu.u[0]=f2bf(f0.x); uu.u[1]=f2bf(f0.y); uu.u[2]=f2bf(f0.z); uu.u[3]=f2bf(f0.w);
    uu.u[4]=f2bf(f1.x); uu.u[5]=f2bf(f1.y); uu.u[6]=f2bf(f1.z); uu.u[7]=f2bf(f1.w);
    *(bf16x8*)(Kw + ((size_t)h*NKEY + p)*HD + dc*8) = uu.v;
}

// ============ Build transposed bf16 value window Vwt[h][d][p] ============
__global__ __launch_bounds__(256)
void kwin_v(const float* __restrict__ vc, const ushort_t* __restrict__ vb,
            ushort_t* __restrict__ Vwt)
{
    __shared__ ushort_t tile[64][40];
    const int t = threadIdx.x;
    const int bp = blockIdx.x, bd = blockIdx.y, h = blockIdx.z;
    const int p_loc = t >> 2, ds0 = (t & 3) * 8;
    const int pr = min(bp*64 + p_loc, NKEY-1);
    const int d = bd*32 + ds0;
    union { ushort_t u[8]; bf16x8 v; } uu;
    if (pr >= CURS) {
        uu.v = *(const bf16x8*)(vb + (size_t)(pr - CURS)*DIM + h*HD + d);
    } else {
        const float* src = vc + ((size_t)pr*NH + h)*HD + d;
        float4 f0 = *(const float4*)src, f1 = *(const float4*)(src+4);
        uu.u[0]=f2bf(f0.x); uu.u[1]=f2bf(f0.y); uu.u[2]=f2bf(f0.z); uu.u[3]=f2bf(f0.w);
        uu.u[4]=f2bf(f1.x); uu.u[5]=f2bf(f1.y); uu.u[6]=f2bf(f1.z); uu.u[7]=f2bf(f1.w);
    }
    *(bf16x8*)&tile[p_loc][ds0] = uu.v;
    __syncthreads();
    const int d_loc = t >> 3, ps = (t & 7) * 8;
    if (bp*64 + ps < NKEY) {
        union { ushort_t u[8]; bf16x8 v; } oo;
        #pragma unroll
        for (int i = 0; i < 8; ++i) oo.u[i] = tile[ps + i][d_loc];
        *(bf16x8*)(Vwt + ((size_t)h*HD + bd*32 + d_loc) * NKEY + bp*64 + ps) = oo.v;
    }
}

// ============ MFMA flash attention: swapped-QK in-register softmax, ============
// ============ double-buffered global_load_lds staging, XOR-swizzled LDS ============
__global__ __launch_bounds__(256)
void attn_kernel(const ushort_t* __restrict__ qb, const ushort_t* __restrict__ Kw,
                 const ushort_t* __restrict__ Vwt, float* __restrict__ Op,
                 float* __restrict__ Ms, float* __restrict__ Ls)
{
    // Linear LDS (global_load_lds requirement); logical layout:
    // Ks: [64 keys][128 d] bf16, 16B-unit XOR-swizzled: LDS[r][u] = K[r][u ^ (r&7)]
    // Vs: [128 d][64 keys] bf16, same swizzle on 16B key-units
    __shared__ ushort_t Ks[2][64*128];   // 2 x 16KB
    __shared__ ushort_t Vs[2][128*64];   // 2 x 16KB

    const int t = threadIdx.x;
    const int w = t >> 6, l = t & 63, quad = l >> 4, l15 = l & 15;
    const int h = blockIdx.y;
    const int q0 = blockIdx.x * 64;
    const int z = blockIdx.z;

    // Q as B-frag: n = l15 = query (w*16+l15), k = quad*8+j over d
    bf16x8 qf[4];
    {
        const int qrow = min(q0 + w*16 + l15, SEQ-1);
        const ushort_t* qp = qb + ((size_t)qrow*NH + h)*HD;
        #pragma unroll
        for (int s = 0; s < 4; ++s) qf[s] = *(const bf16x8*)(qp + s*32 + quad*8);
    }
    f32x4 o[8] = {};
    float m_reg = -1e30f, l_reg = 0.f;

    const ushort_t* Kwh = Kw  + (size_t)h * NKEY * HD;
    const ushort_t* Vwh = Vwt + (size_t)h * HD * NKEY;

    // staging roles (per gld issue i): wave covers 1KB; lane covers 16B
    const int krow_b = w*4 + (l >> 4);   // K row = i*16 + krow_b
    const int kunit  = l & 15;
    const int vrow_b = w*8 + (l >> 3);   // V row (d) = i*32 + vrow_b
    const int vunit  = l & 7;

    const int c_begin = z*CPS, c_end = (z+1)*CPS;

    auto STAGE = [&](int buf, int c) {
        const int p0 = c * 64;
        #pragma unroll
        for (int i = 0; i < 4; ++i) {
            const int row = i*16 + krow_b;
            const int key = min(p0 + row, NKEY-1);
            const int du  = kunit ^ (row & 7);
            gld_lds16(Kwh + (size_t)key*HD + du*8, &Ks[buf][i*2048 + w*512]);
        }
        #pragma unroll
        for (int i = 0; i < 4; ++i) {
            const int d   = i*32 + vrow_b;
            const int ku  = vunit ^ (d & 7);
            const int kb0 = min(p0 + ku*8, NKEY-8);
            gld_lds16(Vwh + (size_t)d*NKEY + kb0, &Vs[buf][i*2048 + w*512]);
        }
    };

    STAGE(0, c_begin);
    __syncthreads();       // compiler drains vmcnt before barrier
    int cur = 0;

    for (int c = c_begin; c < c_end; ++c) {
        if (c + 1 < c_end) STAGE(cur ^ 1, c + 1);   // in flight under compute
        const int p0 = c * 64;

        // QK^T swapped: A = K (m=key), B = Q (n=query)
        f32x4 sf[4];
        #pragma unroll
        for (int kb = 0; kb < 4; ++kb) { f32x4 zz = {0.f,0.f,0.f,0.f}; sf[kb] = zz; }
        #pragma unroll
        for (int s = 0; s < 4; ++s) {
            #pragma unroll
            for (int kb = 0; kb < 4; ++kb) {
                const int row = kb*16 + l15;
                const int usw = (s*4 + quad) ^ (l15 & 7);
                bf16x8 kf = *(const bf16x8*)&Ks[cur][row*128 + usw*8];
                sf[kb] = __builtin_amdgcn_mfma_f32_16x16x32_bf16(kf, qf[s], sf[kb], 0,0,0);
            }
        }

        // in-register online softmax; lane holds 16 keys (kb*16+quad*4+r) of query l15
        float mx = -1e30f;
        #pragma unroll
        for (int kb = 0; kb < 4; ++kb) {
            #pragma unroll
            for (int r = 0; r < 4; ++r) {
                if (p0 + kb*16 + quad*4 + r >= NKEY) sf[kb][r] = -1e30f;
                mx = fmaxf(mx, sf[kb][r]);
            }
        }
        mx = fmaxf(mx, __shfl_xor(mx, 16));
        mx = fmaxf(mx, __shfl_xor(mx, 32));
        const float mn = fmaxf(m_reg, mx);
        const float al = __expf(m_reg - mn);
        m_reg = mn;
        float sum = 0.f;
        #pragma unroll
        for (int kb = 0; kb < 4; ++kb) {
            #pragma unroll
            for (int r = 0; r < 4; ++r) {
                const float ev = __expf(sf[kb][r] - mn);
                sf[kb][r] = ev;
                sum += ev;
            }
        }
        sum += __shfl_xor(sum, 16);
        sum += __shfl_xor(sum, 32);
        l_reg = l_reg * al + sum;

        // P A-frags, lane-local (k-axis permuted consistently with V reads):
        // slot j<4 -> key kb=2ks, r=j ; slot j>=4 -> key kb=2ks+1, r=j-4
        union { unsigned int u32[4]; bf16x8 v; } pf0, pf1;
        pf0.u32[0] = cvt_pk_bf16(sf[0][0], sf[0][1]);
        pf0.u32[1] = cvt_pk_bf16(sf[0][2], sf[0][3]);
        pf0.u32[2] = cvt_pk_bf16(sf[1][0], sf[1][1]);
        pf0.u32[3] = cvt_pk_bf16(sf[1][2], sf[1][3]);
        pf1.u32[0] = cvt_pk_bf16(sf[2][0], sf[2][1]);
        pf1.u32[1] = cvt_pk_bf16(sf[2][2], sf[2][3]);
        pf1.u32[2] = cvt_pk_bf16(sf[3][0], sf[3][1]);
        pf1.u32[3] = cvt_pk_bf16(sf[3][2], sf[3][3]);

        // rescale O (query rows quad*4+r live at lanes quad*4+r)
        float ar[4];
        #pragma unroll
        for (int r = 0; r < 4; ++r) ar[r] = __shfl(al, quad*4 + r);
        #pragma unroll
        for (int nb = 0; nb < 8; ++nb)
            #pragma unroll
            for (int r = 0; r < 4; ++r) o[nb][r] *= ar[r];

        // PV: A = P (m=query), B = V (n=d), k-axis = permuted keys
        #pragma unroll
        for (int ks = 0; ks < 2; ++ks) {
            const bf16x8 pf = ks ? pf1.v : pf0.v;
            #pragma unroll
            for (int nb = 0; nb < 8; ++nb) {
                const int row = nb*16 + l15;                 // d
                const int u0 = (ks*4 +     (quad>>1)) ^ (l15 & 7);
                const int u1 = (ks*4 + 2 + (quad>>1)) ^ (l15 & 7);
                union { unsigned long long q[2]; bf16x8 v; } vf;
                vf.q[0] = *(const unsigned long long*)&Vs[cur][row*64 + u0*8 + (quad&1)*4];
                vf.q[1] = *(const unsigned long long*)&Vs[cur][row*64 + u1*8 + (quad&1)*4];
                o[nb] = __builtin_amdgcn_mfma_f32_16x16x32_bf16(pf, vf.v, o[nb], 0,0,0);
            }
        }

        __syncthreads();   // drains vmcnt(0): next buffer staged; guards overwrite
        cur ^= 1;
    }

    // epilogue: D[m=query rows quad*4+r][n=d col l15]
    {
        float* Opz = Op + (size_t)z * QPAD * NH * HD;
        #pragma unroll
        for (int nb = 0; nb < 8; ++nb) {
            const int col = nb*16 + l15;
            #pragma unroll
            for (int r = 0; r < 4; ++r) {
                const int row = q0 + w*16 + quad*4 + r;   // < 1600, padded
                Opz[((size_t)row*NH + h)*HD + col] = o[nb][r];
            }
        }
        if (quad == 0) {
            const int row = q0 + w*16 + l15;
            Ms[(size_t)z*QPAD*NH + (size_t)row*NH + h] = m_reg;
            Ls[(size_t)z*QPAD*NH + (size_t)row*NH + h] = l_reg;
        }
    }
}

// ============ merge KSPLIT partials (log-sum-exp), bf16 out for out-proj GEMM ============
__global__ __launch_bounds__(256)
void merge_kernel(const float* __restrict__ Op, const float* __restrict__ Ms,
                  const float* __restrict__ Ls, ushort_t* __restrict__ abufb)
{
    const int tid = blockIdx.x*256 + threadIdx.x;   // 1560*12*32
    const int dq = tid & 31;
    const int h = (tid >> 5) % NH;
    const int q = tid / (NH*32);
    const size_t sidx = (size_t)q*NH + h;
    const float m0 = Ms[sidx], m1 = Ms[(size_t)QPAD*NH + sidx];
    const float l0 = Ls[sidx], l1 = Ls[(size_t)QPAD*NH + sidx];
    const float mm = fmaxf(m0, m1);
    const float w0 = __expf(m0 - mm), w1 = __expf(m1 - mm);
    const float inv = 1.0f / (l0*w0 + l1*w1);
    const size_t oidx = sidx*HD + dq*4;
    float4 a = *(const float4*)(Op + oidx);
    float4 b = *(const float4*)(Op + (size_t)QPAD*NH*HD + oidx);
    ushort4 r;
    r.x = f2bf((a.x*w0 + b.x*w1)*inv);
    r.y = f2bf((a.y*w0 + b.y*w1)*inv);
    r.z = f2bf((a.z*w0 + b.z*w1)*inv);
    r.w = f2bf((a.w*w0 + b.w*w1)*inv);
    *(ushort4*)(abufb + (size_t)q*DIM + h*HD + dq*4) = r;
}

extern "C" void kernel_launch(void* const* d_in, const int* in_sizes, int n_in,
                              void* d_out, int out_size, void* d_ws, size_t ws_size,
                              hipStream_t stream)
{
    const float* x     = (const float*)d_in[0];
    const float* freqs = (const float*)d_in[1];
    const float* wq    = (const float*)d_in[2];
    const float* bq    = (const float*)d_in[3];
    const float* wk    = (const float*)d_in[4];
    const float* bk    = (const float*)d_in[5];
    const float* wv    = (const float*)d_in[6];
    const float* bv    = (const float*)d_in[7];
    const float* wo    = (const float*)d_in[8];
    const float* bo    = (const float*)d_in[9];
    const float* gq    = (const float*)d_in[10];
    const float* gk    = (const float*)d_in[11];
    const float* kck   = (const float*)d_in[12];
    const float* kcv   = (const float*)d_in[13];

    char* ws = (char*)d_ws;
    const size_t SZ_B16 = (size_t)SEQ*DIM*2;          // 4,792,320
    const size_t SZ_KW  = (size_t)NH*NKEY*HD*2;       // 19,169,280
    const size_t SZ_OP  = (size_t)KSPLIT*QPAD*NH*HD*4;// 19,660,800
    const size_t SZ_ST  = (size_t)KSPLIT*QPAD*NH*4;   // 153,600
    const size_t SZ_AB  = (size_t)MPAD*DIM*2;         // 5,111,808 (xb & abufb alias)

    ushort_t* qb  = (ushort_t*)(ws);
    ushort_t* kb  = (ushort_t*)(ws + SZ_B16);         // (unused this round)
    ushort_t* vb  = (ushort_t*)(ws + 2*SZ_B16);
    ushort_t* Kw  = (ushort_t*)(ws + 3*SZ_B16);
    ushort_t* Vwt = (ushort_t*)(ws + 3*SZ_B16 + SZ_KW);
    float*    Opb = (float*)   (ws + 3*SZ_B16 + 2*SZ_KW);
    float*    Msp = (float*)   (ws + 3*SZ_B16 + 2*SZ_KW + SZ_OP);
    float*    Lsp = (float*)   (ws + 3*SZ_B16 + 2*SZ_KW + SZ_OP + SZ_ST);
    ushort_t* abufb=(ushort_t*)(ws + 3*SZ_B16 + 2*SZ_KW + SZ_OP + 2*SZ_ST);
    ushort_t* wob = (ushort_t*)(ws + 3*SZ_B16 + 2*SZ_KW + SZ_OP + 2*SZ_ST + SZ_AB);
    // aliases (stream-ordered safe):
    ushort_t* xb   = abufb;   // xb dead before merge writes abufb
    ushort_t* Wqkv = Kw;      // Wqkv dead before kwin_k / rms2 write Kw
    float*    qf   = Opb;     // qf/kf dead before attn writes Opb
    float*    kf   = Opb + (size_t)SEQ*DIM;

    dim3 blk(256);
    (void)kb;

    // 1. bf16 pre-conversion (single fused launch)
    hipLaunchKernelGGL(conv5, dim3(1170 + 4*1152), blk, 0, stream,
                       x, wq, wk, wv, wo, xb, Wqkv, wob);

    // 2. fused QKV projection: [1560,1536] @ [4608,1536]^T
    hipLaunchKernelGGL((gemm128<1>), dim3(36, 13), blk, 0, stream,
                       xb, Wqkv, bq, bk, bv, qf, kf, vb, SEQ, DIM);

    // 3. fused rmsnorm+rope for q (->qb) and k (-> Kw tail rows directly)
    hipLaunchKernelGGL(rms2, dim3(SEQ, 2), blk, 0, stream,
                       qf, kf, gq, gk, freqs, qb, (unsigned int*)Kw);

    // 4. key window cache rows (p < CURS)
    hipLaunchKernelGGL(kwin_k, dim3(NH*CURS*16/256), blk, 0, stream, kck, Kw);

    // 5. transposed value window
    hipLaunchKernelGGL(kwin_v, dim3(98, 4, NH), blk, 0, stream, kcv, vb, Vwt);

    // 6. attention
    hipLaunchKernelGGL(attn_kernel, dim3((SEQ+63)/64, NH, KSPLIT), blk, 0, stream,
                       qb, Kw, Vwt, Opb, Msp, Lsp);

    // 7. merge split-K partials
    hipLaunchKernelGGL(merge_kernel, dim3(SEQ*NH*32/256), blk, 0, stream, Opb, Msp, Lsp, abufb);

    // 8. output projection
    hipLaunchKernelGGL((gemm128<0>), dim3(12, 13), blk, 0, stream,
                       abufb, wob, bo, bo, bo, (float*)d_out, (float*)d_out, (ushort_t*)nullptr, SEQ, DIM);
}